// Round 7
// baseline (12899.736 us; speedup 1.0000x reference)
//
#include <hip/hip_runtime.h>
#include <math.h>

#define T_LEN 512
#define BATCH 128
#define HID   256
#define BH    (BATCH*HID)   // 32768
#define BPB   4             // batch rows per block (R7: was 8)
#define NBG   32            // batch groups (R7: was 16)

// ---------------- helpers ----------------
// fast reciprocal: v_rcp_f32 + 1 Newton step (~0.5 ulp, cheaper than exact div)
__device__ __forceinline__ float frcp(float d) {
    float r = __builtin_amdgcn_rcpf(d);
    return r * fmaf(-d, r, 2.0f);
}
__device__ __forceinline__ float sigmoid_f(float v) {
    return frcp(1.f + __expf(-v));
}
__device__ __forceinline__ float tanh_f(float v) {
    v = fminf(fmaxf(v, -15.f), 15.f);
    const float e = __expf(2.f * v);
    return (e - 1.f) * frcp(e + 1.f);
}
__device__ __forceinline__ float4 ldf4(const float* p) {
    return *reinterpret_cast<const float4*>(p);
}
__device__ __forceinline__ void fma4(float4& a, const float4 v, const float4 w) {
    a.x = fmaf(v.x, w.x, a.x);
    a.y = fmaf(v.y, w.y, a.y);
    a.z = fmaf(v.z, w.z, a.z);
    a.w = fmaf(v.w, w.w, a.w);
}
__device__ __forceinline__ float hsum4(const float4 a) {
    return (a.x + a.y) + (a.z + a.w);
}
// Pin weights into VGPRs (asm def can't be rematerialized into the loop).
// R2: no AGPR forcing. R4: no hand-written pk_fma. R5: no extra register-
// carried loop state (ax/c in regs) — it spills to scratch -> HBM blowup.
__device__ __forceinline__ void pin4(float4& v) {
    asm volatile("" : "+v"(v.x), "+v"(v.y), "+v"(v.z), "+v"(v.w));
}
// agent-scope relaxed atomics: coherent across XCDs, no cache flushes
__device__ __forceinline__ void astore(float* p, float v) {
    __hip_atomic_store(p, v, __ATOMIC_RELAXED, __HIP_MEMORY_SCOPE_AGENT);
}
__device__ __forceinline__ float2 af2(const float* p) {
    unsigned long long u = __hip_atomic_load((const unsigned long long*)p,
                                             __ATOMIC_RELAXED, __HIP_MEMORY_SCOPE_AGENT);
    union { unsigned long long u; float2 f; } c; c.u = u;
    return c.f;
}
__device__ __forceinline__ float4 af4(const float* p) {
    const float2 a = af2(p), b = af2(p + 2);
    return make_float4(a.x, a.y, b.x, b.y);
}
// DPP row_shr prefix reduction within 16-lane groups; lane (kc==15) gets the sum.
template<int CTRL>
__device__ __forceinline__ float dpp_mv(float x) {
    return __int_as_float(__builtin_amdgcn_update_dpp(
        0, __float_as_int(x), CTRL, 0xF, 0xF, true));
}
__device__ __forceinline__ float red16(float x) {
    x += dpp_mv<0x111>(x);  // row_shr:1
    x += dpp_mv<0x112>(x);  // row_shr:2
    x += dpp_mv<0x114>(x);  // row_shr:4
    x += dpp_mv<0x118>(x);  // row_shr:8
    return x;               // valid in lane kc==15 of each 16-group
}

// ---------------- persistent LSTM (R6 skeleton, 4 blocks/CU) ----------------
// R7 change (single variable): grid 512 -> 1024, batch rows/block 8 -> 4,
// bg-groups 16 -> 32. Rationale: R6 showed Occupancy 24% (2 waves/SIMD) with
// ~45% of each step stalled; doubling resident blocks/CU doubles wave-level
// overlap of the uncorrelated stall components (MALL load latency, store
// drains, barrier skew) and halves the per-block crit length before h
// publishes. Everything proven stays:
//  - flag structure: 32 flags/group, 32 poller lanes/block (poll streams
//    only 2x R1 — far from R3's congestion collapse).
//  - XCD locality: bg = bid&31 -> bid%8 = bg%8 constant within a group.
//  - stride-20 LDS rows (conflicts 8x down, R4/R6).
//  - per-step state in LDS (R5: registers spill to scratch -> HBM blowup).
//  - schedule lags: L0 computes h0[s-1] at iter s; L1 computes h1[s-3];
//    input-half GEMV (xact) runs after flag publish into ls_ax.
__global__ __launch_bounds__(256, 4)
void lstm_persist(
    const float* __restrict__ x,
    const float* __restrict__ Wih, const float* __restrict__ Whh,
    const float* __restrict__ bih, const float* __restrict__ bhh,
    float* __restrict__ out,
    float* __restrict__ h0buf,   // 3 * BH (triple-buffered by timestep%3)
    float* __restrict__ h1buf,   // 3 * BH
    int* __restrict__ flags)     // NBG groups x 32 blocks
{
    __shared__ float ls_in[BPB * 640];   // 4 b x 32 rows x 20 (stride-20)
    __shared__ float ls_a [BPB * 16 * 4];  // gate pre-activations [b*16+jp][g]
    __shared__ float ls_ax[BPB * 16 * 4];  // input-half sums for NEXT step
    __shared__ float ls_c [BPB * 16];      // c[b*16+jp]

    const int tid = threadIdx.x;
    const int bid = blockIdx.x;
    const int bg = bid & (NBG - 1);
    const int layer = (bid >> 5) & 1;
    const int jt = bid >> 6;
    const int jp = tid >> 4;
    const int kc = tid & 15;
    const int j = jt * 16 + jp;
    const int Bg0 = bg * BPB;

    const float* Wih_l = Wih + (size_t)layer * 4 * HID * HID;
    const float* Whh_l = Whh + (size_t)layer * 4 * HID * HID;
    const float* bih_l = bih + layer * 4 * HID;
    const float* bhh_l = bhh + layer * 4 * HID;

    // Weights: 4 gates x 16 K-cols per half = 128 floats, pinned VGPRs.
    float4 wih[4][4], whh[4][4];
    float bias[4];
    #pragma unroll
    for (int g = 0; g < 4; ++g) {
        const int row = g * HID + j;             // row in 4H
        const float* pih = Wih_l + (size_t)row * HID + kc * 16;
        const float* phh = Whh_l + (size_t)row * HID + kc * 16;
        #pragma unroll
        for (int m = 0; m < 4; ++m) {
            wih[g][m] = ldf4(pih + m * 4);
            pin4(wih[g][m]);
            whh[g][m] = ldf4(phh + m * 4);
            pin4(whh[g][m]);
        }
        bias[g] = bih_l[row] + bhh_l[row];
        asm volatile("" : "+v"(bias[g]));
    }

    if (tid < BPB * 16) {              // synced by first barrier below
        ls_c[tid] = 0.f;
        #pragma unroll
        for (int g = 0; g < 4; ++g) ls_ax[tid * 4 + g] = 0.f;
    }

    int* myflag = flags + bg * 32 + layer * 16 + jt;

    #pragma unroll 1
    for (int s = 0; s <= T_LEN + 2; ++s) {
        if (s > 0 && tid < 32) {
            // signed compare: 0xAAAAAAAA poison is negative -> blocks until real store
            const int thr = (layer == 0 && tid >= 16) ? (s - 1) : s;
            const int* f = flags + bg * 32 + tid;
            while (__hip_atomic_load(f, __ATOMIC_RELAXED, __HIP_MEMORY_SCOPE_AGENT) < thr)
                __builtin_amdgcn_s_sleep(1);
        }
        __syncthreads();   // B1: inputs published & visible

        // crit: compute h[t] (t = s-1 for L0, s-3 for L1) from recurrent half.
        // xact: input-half partial sums for the step after t (-> ls_ax).
        const bool crit = (layer == 0) ? (s >= 1 && s <= T_LEN) : (s >= 3);
        const bool xact = (layer == 0) ? (s < T_LEN) : (s >= 2 && s <= T_LEN + 1);
        const bool zeroh = (layer == 0) ? (s == 1) : (s == 3);   // h[t-1] = 0

        if (crit || xact) {
            // cols 0..255 = input half | 256..511 = recurrent half
            const float* ph0 = h0buf + (size_t)((s + 1) % 3) * BH;  // h0[s-2]
            const float* ph1 = h1buf + (size_t)((s + 2) % 3) * BH;  // h1[s-4]
            #pragma unroll
            for (int i = 0; i < 2; ++i) {
                const int F = tid + 256 * i;     // f4 index in 4 b x 128
                const int b = F >> 7;
                const int rr = F & 127;          // global col = rr*4
                const size_t row = (size_t)(Bg0 + b) * HID + (rr & 63) * 4;
                float4 v = make_float4(0.f, 0.f, 0.f, 0.f);
                if ((rr >> 6) == 0) {            // input half (slack)
                    if (xact)
                        v = (layer == 0) ? ldf4(x + (size_t)s * BH + row)
                                         : af4(ph0 + row);
                } else if (crit && !zeroh) {     // recurrent half (critical)
                    v = (layer == 0) ? af4(ph0 + row) : af4(ph1 + row);
                }
                // col 4rr -> row rr>>2, float-off (rr&3)*4; row stride 20
                *(float4*)(ls_in + b * 640 + (rr >> 2) * 20 + (rr & 3) * 4) = v;
            }
        }
        __syncthreads();   // B2: staging visible

        if (crit) {
            // ---- CRITICAL: recurrent K=256 GEMV; lane kc -> row 16+kc
            #pragma unroll
            for (int b = 0; b < BPB; ++b) {
                const float4* Lp = (const float4*)(ls_in + b * 640 + (16 + kc) * 20);
                const float4 i0 = Lp[0], i1 = Lp[1], i2 = Lp[2], i3 = Lp[3];
                float4 ac[4];
                #pragma unroll
                for (int g = 0; g < 4; ++g) ac[g] = make_float4(0.f, 0.f, 0.f, 0.f);
                #pragma unroll
                for (int g = 0; g < 4; ++g) {
                    fma4(ac[g], i0, whh[g][0]);
                    fma4(ac[g], i1, whh[g][1]);
                    fma4(ac[g], i2, whh[g][2]);
                    fma4(ac[g], i3, whh[g][3]);
                }
                const float a0 = red16(hsum4(ac[0]));
                const float a1 = red16(hsum4(ac[1]));
                const float a2 = red16(hsum4(ac[2]));
                const float a3 = red16(hsum4(ac[3]));
                if (kc == 15) {   // owner: combine with input-half sums from last iter
                    const int cell = b * 16 + jp;
                    const float* axp = ls_ax + cell * 4;
                    float* ap = ls_a + cell * 4;
                    ap[0] = a0 + bias[0] + axp[0];
                    ap[1] = a1 + bias[1] + axp[1];
                    ap[2] = a2 + bias[2] + axp[2];
                    ap[3] = a3 + bias[3] + axp[3];
                }
            }
        }
        __syncthreads();   // B3: ls_a complete

        if (crit && tid < BPB * 16) {
            // ---- block epilogue: thread = one (b, j) cell; coalesced stores
            const int bb = tid >> 4;
            const int jpp = tid & 15;
            const int t = (layer == 0) ? (s - 1) : (s - 3);
            float* hst = (layer == 0) ? (h0buf + (size_t)((s + 2) % 3) * BH)  // h0[s-1]
                                      : (h1buf + (size_t)(s % 3) * BH);       // h1[s-3]
            const bool last = (t == T_LEN - 1);
            const float* ap = ls_a + tid * 4;
            const float gi = sigmoid_f(ap[0]);
            const float gf = sigmoid_f(ap[1]);
            const float gg = tanh_f   (ap[2]);
            const float go = sigmoid_f(ap[3]);
            const float cold = ls_c[tid];
            const float cnew = fmaf(gf, cold, gi * gg);
            ls_c[tid] = cnew;
            const float h = go * tanh_f(cnew);
            const int B = Bg0 + bb;
            const int jg = jt * 16 + jpp;
            astore(hst + (size_t)B * HID + jg, h);
            if (layer == 1)
                out[(size_t)t * BH + (size_t)B * HID + jg] = h;
            if (last) {
                float* hn  = out + (size_t)T_LEN * BH;
                float* cnp = hn + 2 * BH;
                hn [(size_t)layer * BH + (size_t)B * HID + jg] = h;
                cnp[(size_t)layer * BH + (size_t)B * HID + jg] = cnew;
            }
        }
        __syncthreads();   // B4: h-stores drained (vmcnt(0) before s_barrier)
        if (s <= T_LEN + 1 && tid == 0)
            __hip_atomic_store(myflag, s + 1, __ATOMIC_RELAXED, __HIP_MEMORY_SCOPE_AGENT);

        if (xact) {
            // ---- SLACK: input-half K=256 GEMV for the NEXT step, after the
            // flag is out. lane kc -> row kc; owner writes ls_ax.
            #pragma unroll
            for (int b = 0; b < BPB; ++b) {
                const float4* Lp = (const float4*)(ls_in + b * 640 + kc * 20);
                const float4 i0 = Lp[0], i1 = Lp[1], i2 = Lp[2], i3 = Lp[3];
                float4 ac[4];
                #pragma unroll
                for (int g = 0; g < 4; ++g) ac[g] = make_float4(0.f, 0.f, 0.f, 0.f);
                #pragma unroll
                for (int g = 0; g < 4; ++g) {
                    fma4(ac[g], i0, wih[g][0]);
                    fma4(ac[g], i1, wih[g][1]);
                    fma4(ac[g], i2, wih[g][2]);
                    fma4(ac[g], i3, wih[g][3]);
                }
                const float a0 = red16(hsum4(ac[0]));
                const float a1 = red16(hsum4(ac[1]));
                const float a2 = red16(hsum4(ac[2]));
                const float a3 = red16(hsum4(ac[3]));
                if (kc == 15) {
                    float* axp = ls_ax + (b * 16 + jp) * 4;
                    axp[0] = a0;
                    axp[1] = a1;
                    axp[2] = a2;
                    axp[3] = a3;
                }
            }
        }
    }
}

extern "C" void kernel_launch(void* const* d_in, const int* in_sizes, int n_in,
                              void* d_out, int out_size, void* d_ws, size_t ws_size,
                              hipStream_t stream) {
    const float* x   = (const float*)d_in[0];
    const float* Wih = (const float*)d_in[1];
    const float* Whh = (const float*)d_in[2];
    const float* bih = (const float*)d_in[3];
    const float* bhh = (const float*)d_in[4];
    float* out = (float*)d_out;

    float* h0 = (float*)d_ws;          // 3*BH
    float* h1 = h0 + 3 * BH;           // 3*BH
    int* flags = (int*)(h1 + 3 * BH);  // NBG*32 = 1024 ints, poison-proof

    hipLaunchKernelGGL(lstm_persist, dim3(NBG * 32), dim3(256), 0, stream,
                       x, Wih, Whh, bih, bhh, out, h0, h1, flags);
}

// Round 8
// 4268.457 us; speedup vs baseline: 3.0221x; 3.0221x over previous
//
#include <hip/hip_runtime.h>
#include <math.h>

#define T_LEN 512
#define BATCH 128
#define HID   256
#define BH    (BATCH*HID)   // 32768

// ---------------- helpers ----------------
// fast reciprocal: v_rcp_f32 + 1 Newton step (~0.5 ulp, cheaper than exact div)
__device__ __forceinline__ float frcp(float d) {
    float r = __builtin_amdgcn_rcpf(d);
    return r * fmaf(-d, r, 2.0f);
}
__device__ __forceinline__ float sigmoid_f(float v) {
    return frcp(1.f + __expf(-v));
}
__device__ __forceinline__ float tanh_f(float v) {
    v = fminf(fmaxf(v, -15.f), 15.f);
    const float e = __expf(2.f * v);
    return (e - 1.f) * frcp(e + 1.f);
}
__device__ __forceinline__ float4 ldf4(const float* p) {
    return *reinterpret_cast<const float4*>(p);
}
__device__ __forceinline__ void fma4(float4& a, const float4 v, const float4 w) {
    a.x = fmaf(v.x, w.x, a.x);
    a.y = fmaf(v.y, w.y, a.y);
    a.z = fmaf(v.z, w.z, a.z);
    a.w = fmaf(v.w, w.w, a.w);
}
__device__ __forceinline__ float hsum4(const float4 a) {
    return (a.x + a.y) + (a.z + a.w);
}
// Pin weights into VGPRs (asm def can't be rematerialized into the loop).
// R2: no AGPR forcing. R4: no hand-written pk_fma. R5: no extra register-
// carried loop state. R7: never let the waves/EU target shrink the budget
// below the pinned-weight footprint (VGPR 64 + scratch spills = 15 GB FETCH).
__device__ __forceinline__ void pin4(float4& v) {
    asm volatile("" : "+v"(v.x), "+v"(v.y), "+v"(v.z), "+v"(v.w));
}
// agent-scope relaxed atomics: coherent across XCDs, no cache flushes
__device__ __forceinline__ void astore(float* p, float v) {
    __hip_atomic_store(p, v, __ATOMIC_RELAXED, __HIP_MEMORY_SCOPE_AGENT);
}
__device__ __forceinline__ float2 af2(const float* p) {
    unsigned long long u = __hip_atomic_load((const unsigned long long*)p,
                                             __ATOMIC_RELAXED, __HIP_MEMORY_SCOPE_AGENT);
    union { unsigned long long u; float2 f; } c; c.u = u;
    return c.f;
}
__device__ __forceinline__ float4 af4(const float* p) {
    const float2 a = af2(p), b = af2(p + 2);
    return make_float4(a.x, a.y, b.x, b.y);
}
// DPP row_shr prefix reduction within 16-lane groups; lane (kc==15) gets the sum.
template<int CTRL>
__device__ __forceinline__ float dpp_mv(float x) {
    return __int_as_float(__builtin_amdgcn_update_dpp(
        0, __float_as_int(x), CTRL, 0xF, 0xF, true));
}
__device__ __forceinline__ float red16(float x) {
    x += dpp_mv<0x111>(x);  // row_shr:1
    x += dpp_mv<0x112>(x);  // row_shr:2
    x += dpp_mv<0x114>(x);  // row_shr:4
    x += dpp_mv<0x118>(x);  // row_shr:8
    return x;               // valid in lane kc==15 of each 16-group
}

// ---------- persistent LSTM: 512-thread blocks, wave phase-specialization ----------
// grid 512 x 512 threads, 2 blocks/CU (16 waves/CU = 4 waves/SIMD — 2x R6's TLP).
// Same bid decode / flag structure / poll army / LDS layout / schedule as R6:
//  - IDENTITY decode: bg = bid&15 keeps each 32-block bg-group on one XCD (R2).
//  - 32 block flags/group, 32 poller lanes/block (R3: wider polling collapses).
//  - stride-20 LDS rows (R4/R6: conflicts 8x down).
//  - per-step state in LDS (R5: register-carried state spills to scratch).
//  - lags: L0 computes h0[s-1] at iter s; L1 computes h1[s-3].
//
// NEW (R8): waves 0-3 = CRIT group (holds only W_hh, 64 floats/thread);
// waves 4-7 = XACT group (holds only W_ih). Both run their K=256 GEMV in
// PARALLEL between B2 and B3. ls_ax is double-buffered: crit reads [s&1]
// (written by xact at s-1), xact writes [(s+1)&1]. Halving the per-thread
// weight footprint is what makes the 128-VGPR budget at 4 waves/EU feasible
// (R7's failure) — and the weights become fully register-resident for the
// first time (R1/R6's VGPR=100 < 128 proved partial re-streaming).
__global__ __launch_bounds__(512)
__attribute__((amdgpu_waves_per_eu(4, 4)))
void lstm_persist(
    const float* __restrict__ x,
    const float* __restrict__ Wih, const float* __restrict__ Whh,
    const float* __restrict__ bih, const float* __restrict__ bhh,
    float* __restrict__ out,
    float* __restrict__ h0buf,   // 3 * BH (triple-buffered by timestep%3)
    float* __restrict__ h1buf,   // 3 * BH
    int* __restrict__ flags)     // 16 groups x 32 blocks
{
    __shared__ float ls_in[8 * 640];       // 8 b x 32 rows x 20 (stride-20)
    __shared__ float ls_a [128 * 4];       // gate pre-activations [b*16+jp][g]
    __shared__ float ls_ax[2][128 * 4];    // input-half sums, double-buffered
    __shared__ float ls_c [128];           // c[b*16+jp]

    const int tid = threadIdx.x;
    const int bid = blockIdx.x;
    const int bg = bid & 15;
    const int layer = (bid >> 4) & 1;
    const int jt = bid >> 5;
    const int tl = tid & 255;           // index within the 256-thread group
    const int jp = tl >> 4;
    const int kc = tl & 15;
    const int j = jt * 16 + jp;
    const int Bg0 = bg * 8;
    const bool iscrit = (tid < 256);    // waves 0-3 crit, 4-7 xact (wave-uniform)

    const float* Wih_l = Wih + (size_t)layer * 4 * HID * HID;
    const float* Whh_l = Whh + (size_t)layer * 4 * HID * HID;
    const float* bih_l = bih + layer * 4 * HID;
    const float* bhh_l = bhh + layer * 4 * HID;

    // ONE weight set per thread: crit -> W_hh slice, xact -> W_ih slice.
    // 4 gates x 16 K-cols = 64 floats, pinned, fully resident.
    const float* Wsel = iscrit ? Whh_l : Wih_l;
    float4 w[4][4];
    float bias[4];
    #pragma unroll
    for (int g = 0; g < 4; ++g) {
        const int row = g * HID + j;             // row in 4H
        const float* pw = Wsel + (size_t)row * HID + kc * 16;
        #pragma unroll
        for (int m = 0; m < 4; ++m) {
            w[g][m] = ldf4(pw + m * 4);
            pin4(w[g][m]);
        }
        bias[g] = bih_l[row] + bhh_l[row];       // used by crit owners only
        asm volatile("" : "+v"(bias[g]));
    }

    if (tid < 128) ls_c[tid] = 0.f;    // synced by first barrier below
    // ls_ax needs no init: first crit reads (L0 s=1 -> buf1, L1 s=3 -> buf1)
    // are written by xact at s=0 / s=2 respectively.

    // LDS row this thread's GEMV reads: rec half rows 16..31, input rows 0..15.
    const int lrow = iscrit ? (16 + kc) : kc;

    int* myflag = flags + bg * 32 + layer * 16 + jt;

    #pragma unroll 1
    for (int s = 0; s <= T_LEN + 2; ++s) {
        if (s > 0 && tid < 32) {
            // signed compare: 0xAAAAAAAA poison is negative -> blocks until real store
            const int thr = (layer == 0 && tid >= 16) ? (s - 1) : s;
            const int* f = flags + bg * 32 + tid;
            while (__hip_atomic_load(f, __ATOMIC_RELAXED, __HIP_MEMORY_SCOPE_AGENT) < thr)
                __builtin_amdgcn_s_sleep(1);
        }
        __syncthreads();   // B1: inputs published & visible

        // crit: compute h[t] (t = s-1 for L0, s-3 for L1) from recurrent half.
        // xact: input-half partial sums for the step after t (-> ls_ax[(s+1)&1]).
        const bool crit = (layer == 0) ? (s >= 1 && s <= T_LEN) : (s >= 3);
        const bool xact = (layer == 0) ? (s < T_LEN) : (s >= 2 && s <= T_LEN + 1);
        const bool zeroh = (layer == 0) ? (s == 1) : (s == 3);   // h[t-1] = 0

        if (crit || xact) {
            // cols 0..255 = input half | 256..511 = recurrent half
            const float* ph0 = h0buf + (size_t)((s + 1) % 3) * BH;  // h0[s-2]
            const float* ph1 = h1buf + (size_t)((s + 2) % 3) * BH;  // h1[s-4]
            #pragma unroll
            for (int i = 0; i < 2; ++i) {
                const int F = tid + 512 * i;     // f4 index in 8 b x 128
                const int b = F >> 7;
                const int rr = F & 127;          // global col = rr*4
                const size_t row = (size_t)(Bg0 + b) * HID + (rr & 63) * 4;
                float4 v = make_float4(0.f, 0.f, 0.f, 0.f);
                if ((rr >> 6) == 0) {            // input half
                    if (xact)
                        v = (layer == 0) ? ldf4(x + (size_t)s * BH + row)
                                         : af4(ph0 + row);
                } else if (crit && !zeroh) {     // recurrent half (critical)
                    v = (layer == 0) ? af4(ph0 + row) : af4(ph1 + row);
                }
                // col 4rr -> row rr>>2, float-off (rr&3)*4; row stride 20
                *(float4*)(ls_in + b * 640 + (rr >> 2) * 20 + (rr & 3) * 4) = v;
            }
        }
        __syncthreads();   // B2: staging visible

        // ---- PARALLEL GEMV phase: crit waves on rec half, xact waves on input
        // half, simultaneously (separate SIMD issue streams).
        if (iscrit ? crit : xact) {
            #pragma unroll 2
            for (int b = 0; b < 8; ++b) {
                const float4* Lp = (const float4*)(ls_in + b * 640 + lrow * 20);
                const float4 i0 = Lp[0], i1 = Lp[1], i2 = Lp[2], i3 = Lp[3];
                float4 ac[4];
                #pragma unroll
                for (int g = 0; g < 4; ++g) ac[g] = make_float4(0.f, 0.f, 0.f, 0.f);
                #pragma unroll
                for (int g = 0; g < 4; ++g) {
                    fma4(ac[g], i0, w[g][0]);
                    fma4(ac[g], i1, w[g][1]);
                    fma4(ac[g], i2, w[g][2]);
                    fma4(ac[g], i3, w[g][3]);
                }
                const float a0 = red16(hsum4(ac[0]));
                const float a1 = red16(hsum4(ac[1]));
                const float a2 = red16(hsum4(ac[2]));
                const float a3 = red16(hsum4(ac[3]));
                if (kc == 15) {
                    const int cell = b * 16 + jp;
                    if (iscrit) {
                        // combine with input-half sums computed by xact at s-1
                        const float* axp = &ls_ax[s & 1][cell * 4];
                        float* ap = ls_a + cell * 4;
                        ap[0] = a0 + bias[0] + axp[0];
                        ap[1] = a1 + bias[1] + axp[1];
                        ap[2] = a2 + bias[2] + axp[2];
                        ap[3] = a3 + bias[3] + axp[3];
                    } else {
                        float* axp = &ls_ax[(s + 1) & 1][cell * 4];
                        axp[0] = a0;
                        axp[1] = a1;
                        axp[2] = a2;
                        axp[3] = a3;
                    }
                }
            }
        }
        __syncthreads();   // B3: ls_a complete (and ls_ax[(s+1)&1] written)

        if (crit && tid < 128) {
            // ---- block epilogue: thread = one (b, j) cell; coalesced stores
            const int bb = tid >> 4;
            const int jpp = tid & 15;
            const int t = (layer == 0) ? (s - 1) : (s - 3);
            float* hst = (layer == 0) ? (h0buf + (size_t)((s + 2) % 3) * BH)  // h0[s-1]
                                      : (h1buf + (size_t)(s % 3) * BH);       // h1[s-3]
            const bool last = (t == T_LEN - 1);
            const float* ap = ls_a + tid * 4;
            const float gi = sigmoid_f(ap[0]);
            const float gf = sigmoid_f(ap[1]);
            const float gg = tanh_f   (ap[2]);
            const float go = sigmoid_f(ap[3]);
            const float cold = ls_c[tid];
            const float cnew = fmaf(gf, cold, gi * gg);
            ls_c[tid] = cnew;
            const float h = go * tanh_f(cnew);
            const int B = Bg0 + bb;
            const int jg = jt * 16 + jpp;
            astore(hst + (size_t)B * HID + jg, h);
            if (layer == 1)
                out[(size_t)t * BH + (size_t)B * HID + jg] = h;
            if (last) {
                float* hn  = out + (size_t)T_LEN * BH;
                float* cnp = hn + 2 * BH;
                hn [(size_t)layer * BH + (size_t)B * HID + jg] = h;
                cnp[(size_t)layer * BH + (size_t)B * HID + jg] = cnew;
            }
        }
        __syncthreads();   // B4: h-stores drained (vmcnt(0) before s_barrier)
        if (s <= T_LEN + 1 && tid == 0)
            __hip_atomic_store(myflag, s + 1, __ATOMIC_RELAXED, __HIP_MEMORY_SCOPE_AGENT);
    }
}

extern "C" void kernel_launch(void* const* d_in, const int* in_sizes, int n_in,
                              void* d_out, int out_size, void* d_ws, size_t ws_size,
                              hipStream_t stream) {
    const float* x   = (const float*)d_in[0];
    const float* Wih = (const float*)d_in[1];
    const float* Whh = (const float*)d_in[2];
    const float* bih = (const float*)d_in[3];
    const float* bhh = (const float*)d_in[4];
    float* out = (float*)d_out;

    float* h0 = (float*)d_ws;          // 3*BH
    float* h1 = h0 + 3 * BH;           // 3*BH
    int* flags = (int*)(h1 + 3 * BH);  // 512 ints, poison-proof (signed compare)

    hipLaunchKernelGGL(lstm_persist, dim3(512), dim3(512), 0, stream,
                       x, Wih, Whh, bih, bhh, out, h0, h1, flags);
}